// Round 13
// baseline (1659.624 us; speedup 1.0000x reference)
//
#include <hip/hip_runtime.h>
#include <hip/hip_bf16.h>
#include <stdint.h>

#define HID  4096
#define INTR 14336
#define GS   64
#define TOK  4096
#define GRP1 (HID / GS)
#define GRP2 (INTR / GS)

typedef __attribute__((ext_vector_type(8))) short short8;  // 8 bf16
typedef __attribute__((ext_vector_type(4))) float f32x4;   // 16x16 MFMA acc
typedef unsigned short u16;
typedef unsigned int   u32;

// ---- helpers -------------------------------------------------------------

__device__ __forceinline__ u16 f2b(float x) {
    return __builtin_bit_cast(u16, __float2bfloat16(x));
}
__device__ __forceinline__ u32 pk2(float a, float b) {
    return (u32)f2b(a) | ((u32)f2b(b) << 16);
}
__device__ __forceinline__ u32 dq2(int ca, int cb, float s, float off) {
    return pk2(fmaf((float)ca, s, off), fmaf((float)cb, s, off));
}
__device__ __forceinline__ uint4 dqw(u32 w, float s, float off) {
    uint4 v;
    v.x = dq2((int)( w        & 15), (int)((w >>  4) & 15), s, off);
    v.y = dq2((int)((w >>  8) & 15), (int)((w >> 12) & 15), s, off);
    v.z = dq2((int)((w >> 16) & 15), (int)((w >> 20) & 15), s, off);
    v.w = dq2((int)((w >> 24) & 15), (int)( w >> 28       ), s, off);
    return v;
}
__device__ __forceinline__ void gload16(const void* g, void* l) {
    __builtin_amdgcn_global_load_lds(
        (const __attribute__((address_space(1))) void*)g,
        (__attribute__((address_space(3))) void*)l, 16, 0, 0);
}

// 4-chunk pre-swizzle (64B rows, BK=32): pos = (c&~3)|((c&3)^((r>>1)&3)).
// r10-verified conflict-free for the 16x16x32 fragment read at 64B row pitch.

// swizzled 16B-chunk byte offset within a [rows][32] bf16 LDS tile
#define RPOS(row, fq) ((((fq) ^ (((row) >> 1) & 3)) << 4))

// ---- weight dequant: int32 codes -> bf16, 4-chunk PRE-SWIZZLE -------------

__global__ void dqw_kernel(const int* __restrict__ q, const float* __restrict__ s,
                           const float* __restrict__ z, u16* __restrict__ o, int cols) {
    int c = blockIdx.x * blockDim.x + threadIdx.x;   // 8-elem chunk in row
    int r = blockIdx.y;
    int grp = cols >> 6;
    const int* src = q + (size_t)r * cols + ((size_t)c << 3);
    int4 a = *(const int4*)src;
    int4 b = *(const int4*)(src + 4);
    float sc = s[(size_t)r * grp + (c >> 3)];
    float zz = z[(size_t)r * grp + (c >> 3)];
    float of = -zz * sc;
    uint4 v;
    v.x = dq2(a.x, a.y, sc, of);
    v.y = dq2(a.z, a.w, sc, of);
    v.z = dq2(b.x, b.y, sc, of);
    v.w = dq2(b.z, b.w, sc, of);
    int cs = (c & ~3) | ((c & 3) ^ ((r >> 1) & 3));
    *(uint4*)(o + (size_t)r * cols + ((size_t)cs << 3)) = v;
}

// ---- repack (fallback): int32 -> 8x 4-bit nibbles per u32 -----------------

__global__ void pack_kernel(const int* __restrict__ q, u32* __restrict__ p) {
    int i = blockIdx.x * blockDim.x + threadIdx.x;
    const int4* s = (const int4*)q + (size_t)i * 2;
    int4 a = s[0], b = s[1];
    u32 w = (u32)(a.x & 15)        | ((u32)(a.y & 15) << 4)
          | ((u32)(a.z & 15) << 8) | ((u32)(a.w & 15) << 12)
          | ((u32)(b.x & 15) << 16)| ((u32)(b.y & 15) << 20)
          | ((u32)(b.z & 15) << 24)| ((u32)(b.w & 15) << 28);
    p[i] = w;
}

// ---- hs fp32 -> bf16, 4-chunk PRE-SWIZZLE ---------------------------------

__global__ void cvt_hs_kernel(const float* __restrict__ x, u16* __restrict__ y) {
    int i = blockIdx.x * blockDim.x + threadIdx.x;
    int t = i >> 9;            // HID/8 = 512 chunks per row
    int c = i & 511;
    const float4* xp = (const float4*)x + (size_t)i * 2;
    float4 a = xp[0], b = xp[1];
    uint4 o;
    o.x = pk2(a.x, a.y); o.y = pk2(a.z, a.w);
    o.z = pk2(b.x, b.y); o.w = pk2(b.z, b.w);
    int cs = (c & ~3) | ((c & 3) ^ ((t >> 1) & 3));
    ((uint4*)y)[(size_t)t * 512 + cs] = o;
}

// ---- kernel 2: fused gate+up dual GEMM + SiLU*mul -------------------------
// BM=BN=128, BK=32, 256 threads (4 waves, 2Mx2N of 64x64), dual acc (128 r).
// LDS 48KB (dbuf x (A 8K | B1 8K | B3 8K)) -> 2 blocks/CU = 2 independent
// barrier domains at the same 8 waves/CU (reg-capped). r6 1-barrier schedule.

template<int MODE>
__global__ __launch_bounds__(256, 2) void gateup_kernel(
    const u16* __restrict__ hsb,
    const u16* __restrict__ w1b, const u16* __restrict__ w3b,
    const u32* __restrict__ w1p, const u32* __restrict__ w3p,
    const float* __restrict__ s1, const float* __restrict__ z1,
    const float* __restrict__ s3, const float* __restrict__ z3,
    u16* __restrict__ hout)
{
    __shared__ __align__(16) char smem[49152];

    const int tid  = threadIdx.x;
    const int row0 = blockIdx.x * 128;
    const int col0 = blockIdx.y * 128;

    const int l   = tid & 63;
    const int wid = tid >> 6;      // 0..3
    const int wr  = wid >> 1;      // 0..1 (M)
    const int wc  = wid & 1;       // 0..1 (N)
    const int fq  = l >> 4;        // 0..3
    const int fr  = l & 15;        // 0..15

    f32x4 accg[4][4];
    f32x4 accu[4][4];
#pragma unroll
    for (int m = 0; m < 4; ++m)
#pragma unroll
        for (int n = 0; n < 4; ++n) {
            accg[m][n] = (f32x4){0.f, 0.f, 0.f, 0.f};
            accu[m][n] = (f32x4){0.f, 0.f, 0.f, 0.f};
        }

    // DMA sources: 64B rows -> 4 lanes/row; wave covers 16 rows per 1KB round
    const u16* aSrc  = hsb + (size_t)(row0 + wid * 16 + (l >> 2)) * HID + ((l & 3) << 3);
    const u16* b1Src = w1b + (size_t)(col0 + wid * 16 + (l >> 2)) * HID + ((l & 3) << 3);
    const u16* b3Src = w3b + (size_t)(col0 + wid * 16 + (l >> 2)) * HID + ((l & 3) << 3);

    // MODE 1 state: 2 threads/row, each 2 packed words (= 2 chunks) per tile
    const int br = tid >> 1;           // 0..127
    const int pr = tid & 1;            // word pair select
    const u32* pp1 = w1p + (size_t)(col0 + br) * (HID / 8) + pr * 2;
    const u32* pp3 = w3p + (size_t)(col0 + br) * (HID / 8) + pr * 2;
    const size_t sBase = (size_t)(col0 + br) * GRP1;
    uint2 g1, g3;
    float sc1, zz1, sc3, zz3;

    auto LOADB = [&](int KS) {
        g1 = *(const uint2*)(pp1 + KS * 4);
        g3 = *(const uint2*)(pp3 + KS * 4);
        sc1 = s1[sBase + (KS >> 1)]; zz1 = z1[sBase + (KS >> 1)];
        sc3 = s3[sBase + (KS >> 1)]; zz3 = z3[sBase + (KS >> 1)];
    };

    auto STAGE_A = [&](int KS, int bsel) {
        const int k0 = KS * 32;
        char* base = smem + bsel * 24576;
#pragma unroll
        for (int i = 0; i < 2; ++i)
            gload16(aSrc + (size_t)(i * 64) * HID + k0, base + i * 4096 + (wid << 10));
    };
    auto STAGE_B = [&](int KS, int bsel) {
        const int k0 = KS * 32;
        char* base = smem + bsel * 24576;
#pragma unroll
        for (int i = 0; i < 2; ++i) {
            gload16(b1Src + (size_t)(i * 64) * HID + k0, base + 8192  + i * 4096 + (wid << 10));
            gload16(b3Src + (size_t)(i * 64) * HID + k0, base + 16384 + i * 4096 + (wid << 10));
        }
    };

    auto DEQWB = [&](int bsel) {
        u16* dB1 = (u16*)(smem + bsel * 24576 + 8192);
        u16* dB3 = (u16*)(smem + bsel * 24576 + 16384);
        const float of1 = -zz1 * sc1;
        const float of3 = -zz3 * sc3;
        const int x  = (br >> 1) & 3;
        const int c0 = pr * 2;
        const int p0 = (c0    ) ^ x;
        const int p1 = (c0 + 1) ^ x;
        *(uint4*)(&dB1[br * 32 + (p0 << 3)]) = dqw(g1.x, sc1, of1);
        *(uint4*)(&dB1[br * 32 + (p1 << 3)]) = dqw(g1.y, sc1, of1);
        *(uint4*)(&dB3[br * 32 + (p0 << 3)]) = dqw(g3.x, sc3, of3);
        *(uint4*)(&dB3[br * 32 + (p1 << 3)]) = dqw(g3.y, sc3, of3);
    };

    const int NK = HID / 32;   // 128

    if constexpr (MODE == 0) {
        STAGE_A(0, 0);
        STAGE_B(0, 0);
    } else {
        LOADB(0);
        STAGE_A(0, 0);
        DEQWB(0);
    }
    __syncthreads();

    for (int ks = 0; ks < NK; ++ks) {
        const int nxt = ks + 1 < NK ? ks + 1 : NK - 1;
        const int cur = ks & 1;

        if constexpr (MODE == 0) {
            STAGE_A(nxt, cur ^ 1);
            STAGE_B(nxt, cur ^ 1);
        } else {
            LOADB(nxt);
            STAGE_A(nxt, cur ^ 1);
        }

        const char* Rb = smem + cur * 24576;
        short8 af[4], b1f[4], b3f[4];
#pragma unroll
        for (int m = 0; m < 4; ++m) {
            int row = wr * 64 + m * 16 + fr;
            af[m] = *(const short8*)(Rb + row * 64 + RPOS(row, fq));
        }
#pragma unroll
        for (int n = 0; n < 4; ++n) {
            int row = wc * 64 + n * 16 + fr;
            int off = row * 64 + RPOS(row, fq);
            b1f[n] = *(const short8*)(Rb + 8192  + off);
            b3f[n] = *(const short8*)(Rb + 16384 + off);
        }
#pragma unroll
        for (int m = 0; m < 4; ++m)
#pragma unroll
            for (int n = 0; n < 4; ++n) {
                accg[m][n] = __builtin_amdgcn_mfma_f32_16x16x32_bf16(af[m], b1f[n], accg[m][n], 0, 0, 0);
                accu[m][n] = __builtin_amdgcn_mfma_f32_16x16x32_bf16(af[m], b3f[n], accu[m][n], 0, 0, 0);
            }

        if constexpr (MODE == 1) DEQWB(cur ^ 1);
        __syncthreads();
    }

    // -- epilogue: silu(g)*u -> LDS (4-chunk pre-swizzled positions) -> store
    u16* sO = (u16*)smem;    // [128][128] bf16 = 32 KB
#pragma unroll
    for (int m = 0; m < 4; ++m)
#pragma unroll
        for (int n = 0; n < 4; ++n)
#pragma unroll
            for (int r = 0; r < 4; ++r) {
                int lr = wr * 64 + m * 16 + fq * 4 + r;
                int lc = wc * 64 + n * 16 + fr;
                float g = accg[m][n][r];
                float u = accu[m][n][r];
                float hv = (g / (1.0f + __expf(-g))) * u;
                int c  = lc >> 3;
                int cs = (c & ~3) | ((c & 3) ^ ((lr >> 1) & 3));
                sO[lr * 128 + (cs << 3) + (lc & 7)] = f2b(hv);
            }
    __syncthreads();
#pragma unroll
    for (int it = 0; it < 8; ++it) {
        int idx = it * 256 + tid;          // 16B units, 2048 total
        int row = idx >> 4;                // 16 granules (256B) per row
        int cu  = idx & 15;
        uint4 v = ((const uint4*)sO)[row * 16 + cu];
        *(uint4*)(&hout[(size_t)(row0 + row) * INTR + col0 + (cu << 3)]) = v;
    }
}

// ---- kernel 3: down proj --------------------------------------------------
// BM=BN=128, BK=32, 256 threads (4 waves, 2Mx2N of 64x64), single acc (64 r).
// LDS 32KB dbuf -> 3 blocks/CU (launch_bounds(256,3)).

template<int MODE>
__global__ __launch_bounds__(256, 3) void down_kernel(
    const u16* __restrict__ hb,
    const u16* __restrict__ w2b, const u32* __restrict__ w2p,
    const float* __restrict__ s2, const float* __restrict__ z2,
    float* __restrict__ out)
{
    __shared__ __align__(16) char smem[32768];

    const int tid  = threadIdx.x;
    const int row0 = blockIdx.x * 128;
    const int col0 = blockIdx.y * 128;

    const int l   = tid & 63;
    const int wid = tid >> 6;
    const int wr  = wid >> 1;
    const int wc  = wid & 1;
    const int fq  = l >> 4;
    const int fr  = l & 15;

    f32x4 acc[4][4];
#pragma unroll
    for (int m = 0; m < 4; ++m)
#pragma unroll
        for (int n = 0; n < 4; ++n)
            acc[m][n] = (f32x4){0.f, 0.f, 0.f, 0.f};

    const u16* aSrc = hb  + (size_t)(row0 + wid * 16 + (l >> 2)) * INTR + ((l & 3) << 3);
    const u16* bSrc = w2b + (size_t)(col0 + wid * 16 + (l >> 2)) * INTR + ((l & 3) << 3);

    const int br = tid >> 1;
    const int pr = tid & 1;
    const u32* pp2 = w2p + (size_t)(col0 + br) * (INTR / 8) + pr * 2;
    const size_t sBase = (size_t)(col0 + br) * GRP2;
    uint2 g2;
    float sc, zz;

    auto LOADB = [&](int KS) {
        g2 = *(const uint2*)(pp2 + KS * 4);
        sc = s2[sBase + (KS >> 1)]; zz = z2[sBase + (KS >> 1)];
    };

    auto STAGE_A = [&](int KS, int bsel) {
        const int k0 = KS * 32;
        char* base = smem + bsel * 16384;
#pragma unroll
        for (int i = 0; i < 2; ++i)
            gload16(aSrc + (size_t)(i * 64) * INTR + k0, base + i * 4096 + (wid << 10));
    };
    auto STAGE_B = [&](int KS, int bsel) {
        const int k0 = KS * 32;
        char* base = smem + bsel * 16384;
#pragma unroll
        for (int i = 0; i < 2; ++i)
            gload16(bSrc + (size_t)(i * 64) * INTR + k0, base + 8192 + i * 4096 + (wid << 10));
    };

    auto DEQWB = [&](int bsel) {
        u16* dB = (u16*)(smem + bsel * 16384 + 8192);
        const float of = -zz * sc;
        const int x  = (br >> 1) & 3;
        const int c0 = pr * 2;
        *(uint4*)(&dB[br * 32 + (((c0    ) ^ x) << 3)]) = dqw(g2.x, sc, of);
        *(uint4*)(&dB[br * 32 + (((c0 + 1) ^ x) << 3)]) = dqw(g2.y, sc, of);
    };

    const int NK = INTR / 32;   // 448

    if constexpr (MODE == 0) {
        STAGE_A(0, 0);
        STAGE_B(0, 0);
    } else {
        LOADB(0);
        STAGE_A(0, 0);
        DEQWB(0);
    }
    __syncthreads();

    for (int ks = 0; ks < NK; ++ks) {
        const int nxt = ks + 1 < NK ? ks + 1 : NK - 1;
        const int cur = ks & 1;

        if constexpr (MODE == 0) {
            STAGE_A(nxt, cur ^ 1);
            STAGE_B(nxt, cur ^ 1);
        } else {
            LOADB(nxt);
            STAGE_A(nxt, cur ^ 1);
        }

        const char* Rb = smem + cur * 16384;
        short8 af[4], bf[4];
#pragma unroll
        for (int m = 0; m < 4; ++m) {
            int row = wr * 64 + m * 16 + fr;
            af[m] = *(const short8*)(Rb + row * 64 + RPOS(row, fq));
        }
#pragma unroll
        for (int n = 0; n < 4; ++n) {
            int row = wc * 64 + n * 16 + fr;
            bf[n] = *(const short8*)(Rb + 8192 + row * 64 + RPOS(row, fq));
        }
#pragma unroll
        for (int m = 0; m < 4; ++m)
#pragma unroll
            for (int n = 0; n < 4; ++n)
                acc[m][n] = __builtin_amdgcn_mfma_f32_16x16x32_bf16(af[m], bf[n], acc[m][n], 0, 0, 0);

        if constexpr (MODE == 1) DEQWB(cur ^ 1);
        __syncthreads();
    }

    // -- epilogue: fp32 tile through LDS, two 64-row passes (canonical out)
    float* sO = (float*)smem;   // [64][128] f32 = 32 KB
#pragma unroll
    for (int half = 0; half < 2; ++half) {
        if (half) __syncthreads();
        if (wr == half) {
#pragma unroll
            for (int m = 0; m < 4; ++m)
#pragma unroll
                for (int n = 0; n < 4; ++n)
#pragma unroll
                    for (int r = 0; r < 4; ++r) {
                        int lr = m * 16 + fq * 4 + r;            // 0..63
                        int lc = wc * 64 + n * 16 + fr;          // 0..127
                        int cs = ((((lc >> 2) ^ (lr & 7)) << 2) | (lc & 3));
                        sO[lr * 128 + cs] = acc[m][n][r];
                    }
        }
        __syncthreads();
#pragma unroll
        for (int it = 0; it < 8; ++it) {
            int idx = it * 256 + tid;      // 16B units, 2048 total
            int row = idx >> 5;            // 32 float4 (512B) per row
            int ch  = idx & 31;
            float4 v = ((const float4*)sO)[row * 32 + (ch ^ (row & 7))];
            *(float4*)(&out[(size_t)(row0 + half * 64 + row) * HID + col0 + (ch << 2)]) = v;
        }
    }
}

// ---- launcher --------------------------------------------------------------

extern "C" void kernel_launch(void* const* d_in, const int* in_sizes, int n_in,
                              void* d_out, int out_size, void* d_ws, size_t ws_size,
                              hipStream_t stream) {
    (void)in_sizes; (void)n_in; (void)out_size;

    const float* hs  = (const float*)d_in[0];
    const int*   w1q = (const int*)  d_in[1];
    const float* w1s = (const float*)d_in[2];
    const float* w1z = (const float*)d_in[3];
    const int*   w3q = (const int*)  d_in[4];
    const float* w3s = (const float*)d_in[5];
    const float* w3z = (const float*)d_in[6];
    const int*   w2q = (const int*)  d_in[7];
    const float* w2s = (const float*)d_in[8];
    const float* w2z = (const float*)d_in[9];
    float* out = (float*)d_out;

    const size_t NWRD  = (size_t)INTR * HID / 8;
    const size_t SZ_HSB  = (size_t)TOK * HID;
    const size_t SZ_HMID = (size_t)TOK * INTR;
    const size_t SZ_WB   = (size_t)INTR * HID;

    u16* hsb  = (u16*)d_ws;                        // 4-chunk pre-swizzled bf16
    u16* hmid = hsb + SZ_HSB;                      // 4-chunk pre-swizzled bf16
    u16* wb1  = hmid + SZ_HMID;                    // w1 bf16 (later w2 bf16)
    u16* wb3  = wb1 + SZ_WB;                       // w3 bf16
    u32* w1p  = (u32*)wb1;
    u32* w3p  = w1p + NWRD;
    u32* w2p  = w3p + NWRD;

    const size_t needF = (SZ_HSB + SZ_HMID + 2 * SZ_WB) * 2;
    const size_t needP = (SZ_HSB + SZ_HMID) * 2 + 3 * NWRD * 4;

    cvt_hs_kernel<<<(TOK * HID / 8) / 256, 256, 0, stream>>>(hs, hsb);

    dim3 g2(TOK / 128, INTR / 128);   // (32, 112)
    dim3 g3(TOK / 128, HID / 128);    // (32, 32)

    if (ws_size >= needF) {
        dqw_kernel<<<dim3(HID / 8 / 256, INTR), 256, 0, stream>>>(w1q, w1s, w1z, wb1, HID);
        dqw_kernel<<<dim3(HID / 8 / 256, INTR), 256, 0, stream>>>(w3q, w3s, w3z, wb3, HID);
        gateup_kernel<0><<<g2, 256, 0, stream>>>(hsb, wb1, wb3, nullptr, nullptr,
                                                 nullptr, nullptr, nullptr, nullptr, hmid);
        dqw_kernel<<<dim3(INTR / 8 / 256, HID), 256, 0, stream>>>(w2q, w2s, w2z, wb1, INTR);
        down_kernel<0><<<g3, 256, 0, stream>>>(hmid, wb1, nullptr, nullptr, nullptr, out);
    } else if (ws_size >= needP) {
        const int pgrid = (int)(NWRD / 256);
        pack_kernel<<<pgrid, 256, 0, stream>>>(w1q, w1p);
        pack_kernel<<<pgrid, 256, 0, stream>>>(w3q, w3p);
        pack_kernel<<<pgrid, 256, 0, stream>>>(w2q, w2p);
        gateup_kernel<1><<<g2, 256, 0, stream>>>(hsb, nullptr, nullptr, w1p, w3p,
                                                 w1s, w1z, w3s, w3z, hmid);
        down_kernel<1><<<g3, 256, 0, stream>>>(hmid, nullptr, w2p, w2s, w2z, out);
    }
}

// Round 14
// 1383.663 us; speedup vs baseline: 1.1994x; 1.1994x over previous
//
#include <hip/hip_runtime.h>
#include <hip/hip_bf16.h>
#include <stdint.h>

#define HID  4096
#define INTR 14336
#define GS   64
#define TOK  4096
#define GRP1 (HID / GS)
#define GRP2 (INTR / GS)

typedef __attribute__((ext_vector_type(8))) short short8;  // 8 bf16
typedef __attribute__((ext_vector_type(4))) float f32x4;   // 16x16 MFMA acc
typedef unsigned short u16;
typedef unsigned int   u32;

// ---- helpers -------------------------------------------------------------

__device__ __forceinline__ u16 f2b(float x) {
    return __builtin_bit_cast(u16, __float2bfloat16(x));
}
__device__ __forceinline__ u32 pk2(float a, float b) {
    return (u32)f2b(a) | ((u32)f2b(b) << 16);
}
__device__ __forceinline__ u32 dq2(int ca, int cb, float s, float off) {
    return pk2(fmaf((float)ca, s, off), fmaf((float)cb, s, off));
}
__device__ __forceinline__ uint4 dqw(u32 w, float s, float off) {
    uint4 v;
    v.x = dq2((int)( w        & 15), (int)((w >>  4) & 15), s, off);
    v.y = dq2((int)((w >>  8) & 15), (int)((w >> 12) & 15), s, off);
    v.z = dq2((int)((w >> 16) & 15), (int)((w >> 20) & 15), s, off);
    v.w = dq2((int)((w >> 24) & 15), (int)( w >> 28       ), s, off);
    return v;
}
__device__ __forceinline__ void gload16(const void* g, void* l) {
    __builtin_amdgcn_global_load_lds(
        (const __attribute__((address_space(1))) void*)g,
        (__attribute__((address_space(3))) void*)l, 16, 0, 0);
}

// 4-chunk swizzled 16B-chunk byte offset within a [rows][32] bf16 LDS tile
// (r10-verified conflict-free for the 16x16x32 fragment read at 64B pitch)
#define RPOS(row, fq) ((((fq) ^ (((row) >> 1) & 3)) << 4))

// ---- weight dequant: int32 codes -> bf16, PRE-SWIZZLED --------------------
// SW=0: 8-chunk  pos = (c&~7)|((c&7)^(r&7))       (128B rows, BK=64 readers)
// SW=1: 4-chunk  pos = (c&~3)|((c&3)^((r>>1)&3))  (64B rows,  BK=32 readers)

template<int SW>
__global__ void dqw_kernel(const int* __restrict__ q, const float* __restrict__ s,
                           const float* __restrict__ z, u16* __restrict__ o, int cols) {
    int c = blockIdx.x * blockDim.x + threadIdx.x;   // 8-elem chunk in row
    int r = blockIdx.y;
    int grp = cols >> 6;
    const int* src = q + (size_t)r * cols + ((size_t)c << 3);
    int4 a = *(const int4*)src;
    int4 b = *(const int4*)(src + 4);
    float sc = s[(size_t)r * grp + (c >> 3)];
    float zz = z[(size_t)r * grp + (c >> 3)];
    float of = -zz * sc;
    uint4 v;
    v.x = dq2(a.x, a.y, sc, of);
    v.y = dq2(a.z, a.w, sc, of);
    v.z = dq2(b.x, b.y, sc, of);
    v.w = dq2(b.z, b.w, sc, of);
    int cs;
    if constexpr (SW == 0) cs = (c & ~7) | ((c & 7) ^ (r & 7));
    else                   cs = (c & ~3) | ((c & 3) ^ ((r >> 1) & 3));
    *(uint4*)(o + (size_t)r * cols + ((size_t)cs << 3)) = v;
}

// ---- repack (fallback): int32 -> 8x 4-bit nibbles per u32 -----------------

__global__ void pack_kernel(const int* __restrict__ q, u32* __restrict__ p) {
    int i = blockIdx.x * blockDim.x + threadIdx.x;
    const int4* s = (const int4*)q + (size_t)i * 2;
    int4 a = s[0], b = s[1];
    u32 w = (u32)(a.x & 15)        | ((u32)(a.y & 15) << 4)
          | ((u32)(a.z & 15) << 8) | ((u32)(a.w & 15) << 12)
          | ((u32)(b.x & 15) << 16)| ((u32)(b.y & 15) << 20)
          | ((u32)(b.z & 15) << 24)| ((u32)(b.w & 15) << 28);
    p[i] = w;
}

// ---- hs fp32 -> bf16, 4-chunk PRE-SWIZZLE (gateup A, BK=32) ---------------

__global__ void cvt_hs_kernel(const float* __restrict__ x, u16* __restrict__ y) {
    int i = blockIdx.x * blockDim.x + threadIdx.x;
    int t = i >> 9;            // HID/8 = 512 chunks per row
    int c = i & 511;
    const float4* xp = (const float4*)x + (size_t)i * 2;
    float4 a = xp[0], b = xp[1];
    uint4 o;
    o.x = pk2(a.x, a.y); o.y = pk2(a.z, a.w);
    o.z = pk2(b.x, b.y); o.w = pk2(b.z, b.w);
    int cs = (c & ~3) | ((c & 3) ^ ((t >> 1) & 3));
    ((uint4*)y)[(size_t)t * 512 + cs] = o;
}

// ---- kernel 2: fused gate+up dual GEMM + SiLU*mul -------------------------
// BM=256 BN=128 BK=32, 512 threads (8 waves, 4Mx2N of 64x64 dual).
// MODE 0: 3-deep LDS rotation (3 x 32KB), counted vmcnt(4) + raw s_barrier —
//         the tile-(t+2) DMAs stay in flight ACROSS the barrier (T4).
// MODE 1: single-buffer fallback from packed nibbles.

template<int MODE>
__global__ __launch_bounds__(512) void gateup_kernel(
    const u16* __restrict__ hsb,
    const u16* __restrict__ w1b, const u16* __restrict__ w3b,
    const u32* __restrict__ w1p, const u32* __restrict__ w3p,
    const float* __restrict__ s1, const float* __restrict__ z1,
    const float* __restrict__ s3, const float* __restrict__ z3,
    u16* __restrict__ hout)
{
    __shared__ __align__(16) char smem[98304];   // 3 x (A 16K | B1 8K | B3 8K)

    const int tid  = threadIdx.x;
    const int row0 = blockIdx.x * 256;
    const int col0 = blockIdx.y * 128;

    const int l   = tid & 63;
    const int wid = tid >> 6;      // 0..7
    const int wr  = wid >> 1;      // 0..3 (M)
    const int wc  = wid & 1;       // 0..1 (N)
    const int fq  = l >> 4;        // 0..3
    const int fr  = l & 15;        // 0..15

    f32x4 accg[4][4];
    f32x4 accu[4][4];
#pragma unroll
    for (int m = 0; m < 4; ++m)
#pragma unroll
        for (int n = 0; n < 4; ++n) {
            accg[m][n] = (f32x4){0.f, 0.f, 0.f, 0.f};
            accu[m][n] = (f32x4){0.f, 0.f, 0.f, 0.f};
        }

    // DMA sources: 64B rows -> 4 lanes/row, 16 rows per wave instruction
    const u16* aSrc  = hsb + (size_t)(row0 + (l >> 2)) * HID + ((l & 3) << 3);
    const u16* b1Src = w1b + (size_t)(col0 + (l >> 2)) * HID + ((l & 3) << 3);
    const u16* b3Src = w3b + (size_t)(col0 + (l >> 2)) * HID + ((l & 3) << 3);

    // A: 256x32 = 16KB -> 2 instr/thread (blocks 2wid, 2wid+1 of 16 rows)
    auto STAGE_A = [&](int KS, int bsel) {
        const int k0 = KS * 32;
        char* base = smem + bsel * 32768;
#pragma unroll
        for (int i = 0; i < 2; ++i) {
            int blk = wid * 2 + i;               // 0..15
            gload16(aSrc + (size_t)(blk * 16) * HID + k0, base + (blk << 10));
        }
    };
    // B1,B3: 128x32 = 8KB each -> 1 instr/thread each (block wid of 16 rows)
    auto STAGE_B = [&](int KS, int bsel) {
        const int k0 = KS * 32;
        char* base = smem + bsel * 32768;
        gload16(b1Src + (size_t)(wid * 16) * HID + k0, base + 16384 + (wid << 10));
        gload16(b3Src + (size_t)(wid * 16) * HID + k0, base + 24576 + (wid << 10));
    };

    auto MFMA_TILE = [&](const char* Rb) {
        short8 af[4], b1f[4], b3f[4];
#pragma unroll
        for (int m = 0; m < 4; ++m) {
            int row = wr * 64 + m * 16 + fr;
            af[m] = *(const short8*)(Rb + row * 64 + RPOS(row, fq));
        }
#pragma unroll
        for (int n = 0; n < 4; ++n) {
            int row = wc * 64 + n * 16 + fr;
            int off = row * 64 + RPOS(row, fq);
            b1f[n] = *(const short8*)(Rb + 16384 + off);
            b3f[n] = *(const short8*)(Rb + 24576 + off);
        }
#pragma unroll
        for (int m = 0; m < 4; ++m)
#pragma unroll
            for (int n = 0; n < 4; ++n) {
                accg[m][n] = __builtin_amdgcn_mfma_f32_16x16x32_bf16(af[m], b1f[n], accg[m][n], 0, 0, 0);
                accu[m][n] = __builtin_amdgcn_mfma_f32_16x16x32_bf16(af[m], b3f[n], accu[m][n], 0, 0, 0);
            }
    };

    const int NK = HID / 32;   // 128

    if constexpr (MODE == 0) {
        // prologue: tiles 0 and 1 in flight; drain tile 0 only (vmcnt 4)
        STAGE_A(0, 0); STAGE_B(0, 0);
        STAGE_A(1, 1); STAGE_B(1, 1);
        asm volatile("s_waitcnt vmcnt(4)" ::: "memory");
        __builtin_amdgcn_s_barrier();
        __builtin_amdgcn_sched_barrier(0);

        for (int t = 0; t < NK; ++t) {
            const int nxt = (t + 2 < NK) ? t + 2 : NK - 1;
            const int wp  = (t + 2) % 3;
            const int rp  = t % 3;

            STAGE_A(nxt, wp);
            STAGE_B(nxt, wp);

            MFMA_TILE(smem + rp * 32768);

            // drain tile t+1 only; tile t+2 stays in flight across barrier
            asm volatile("s_waitcnt vmcnt(4)" ::: "memory");
            __builtin_amdgcn_s_barrier();
            __builtin_amdgcn_sched_barrier(0);
        }
        asm volatile("s_waitcnt vmcnt(0)" ::: "memory");
        __syncthreads();
    } else {
        // MODE 1 fallback: single buffer, packed nibbles, 2 barriers/step
        const int br = tid >> 2;           // 0..127
        const int bc = tid & 3;            // chunk 0..3
        const u32* pp1 = w1p + (size_t)(col0 + br) * (HID / 8) + bc;
        const u32* pp3 = w3p + (size_t)(col0 + br) * (HID / 8) + bc;
        const size_t sBase = (size_t)(col0 + br) * GRP1;
        u16* dB1 = (u16*)(smem + 16384);
        u16* dB3 = (u16*)(smem + 24576);
        const int ps = (bc ^ ((br >> 1) & 3)) << 3;

        for (int ks = 0; ks < NK; ++ks) {
            u32 g1 = pp1[ks * 4];
            u32 g3 = pp3[ks * 4];
            float sc1 = s1[sBase + (ks >> 1)], zz1 = z1[sBase + (ks >> 1)];
            float sc3 = s3[sBase + (ks >> 1)], zz3 = z3[sBase + (ks >> 1)];
            __syncthreads();   // previous tile fully read
            STAGE_A(ks, 0);
            *(uint4*)(&dB1[br * 32 + ps]) = dqw(g1, sc1, -zz1 * sc1);
            *(uint4*)(&dB3[br * 32 + ps]) = dqw(g3, sc3, -zz3 * sc3);
            __syncthreads();   // drain DMAs + ds_writes
            MFMA_TILE(smem);
        }
        __syncthreads();
    }

    // -- epilogue: silu(g)*u -> LDS (8-chunk pre-swizzled positions for the
    //    down kernel's DMA staging) -> coalesced stores (r12 verbatim)
    u16* sO = (u16*)smem;    // [256][128] bf16 = 64 KB
#pragma unroll
    for (int m = 0; m < 4; ++m)
#pragma unroll
        for (int n = 0; n < 4; ++n)
#pragma unroll
            for (int r = 0; r < 4; ++r) {
                int lr = wr * 64 + m * 16 + fq * 4 + r;
                int lc = wc * 64 + n * 16 + fr;
                float g = accg[m][n][r];
                float u = accu[m][n][r];
                float hv = (g / (1.0f + __expf(-g))) * u;
                int cs = ((((lc >> 3) ^ (lr & 7)) << 3) | (lc & 7));
                sO[lr * 128 + cs] = f2b(hv);
            }
    __syncthreads();
#pragma unroll
    for (int it = 0; it < 8; ++it) {
        int idx = it * 512 + tid;          // 16B units
        int row = idx >> 4;
        int cu  = idx & 15;
        uint4 v = ((const uint4*)sO)[row * 16 + cu];
        *(uint4*)(&hout[(size_t)(row0 + row) * INTR + col0 + (cu << 3)]) = v;
    }
}

// ---- kernel 3: down proj (r12 verbatim — measured best) --------------------
// BM=256 BN=256 BK=64, 8 waves (2Mx4N), wave tile 128x64, 16x16x32 MFMA.

template<int MODE>
__global__ __launch_bounds__(512) void down_kernel(
    const u16* __restrict__ hb,
    const u16* __restrict__ w2b, const u32* __restrict__ w2p,
    const float* __restrict__ s2, const float* __restrict__ z2,
    float* __restrict__ out)
{
    __shared__ __align__(16) char smem[131072];   // 2 x (A 32K | B 32K)

    const int tid  = threadIdx.x;
    const int row0 = blockIdx.x * 256;
    const int col0 = blockIdx.y * 256;

    const int l   = tid & 63;
    const int wid = tid >> 6;
    const int wr  = wid >> 2;
    const int wc  = wid & 3;
    const int fq  = l >> 4;
    const int fr  = l & 15;

    f32x4 acc[8][4];
#pragma unroll
    for (int m = 0; m < 8; ++m)
#pragma unroll
        for (int n = 0; n < 4; ++n)
            acc[m][n] = (f32x4){0.f, 0.f, 0.f, 0.f};

    const u16* aSrc = hb  + (size_t)(row0 + (l >> 3)) * INTR + ((l & 7) << 3);
    const u16* bSrc = w2b + (size_t)(col0 + (l >> 3)) * INTR + ((l & 7) << 3);

    const int br  = tid >> 1;
    const int bc0 = (tid & 1) << 2;
    const int r7  = br & 7;
    const u32* pp2 = w2p + (size_t)(col0 + br) * (INTR / 8) + bc0;
    const size_t sBase = (size_t)(col0 + br) * GRP2;
    uint4 g2d;
    float sc, zz;

    auto LOADB = [&](int KS) {
        g2d = *(const uint4*)(pp2 + KS * 8);
        sc = s2[sBase + KS]; zz = z2[sBase + KS];
    };

    auto STAGE_A = [&](int KS, int bsel) {
        const int k0 = KS * 64;
        char* base = smem + bsel * 65536;
#pragma unroll
        for (int i = 0; i < 4; ++i) {
            int blk = wid * 4 + i;
            gload16(aSrc + (size_t)(blk * 8) * INTR + k0, base + (blk << 10));
        }
    };

    auto STAGE_B = [&](int KS, int bsel) {
        const int k0 = KS * 64;
        char* base = smem + bsel * 65536;
#pragma unroll
        for (int i = 0; i < 4; ++i) {
            int blk = wid * 4 + i;
            gload16(bSrc + (size_t)(blk * 8) * INTR + k0, base + 32768 + (blk << 10));
        }
    };

    auto DEQWB = [&](int bsel) {
        u16* dB = (u16*)(smem + bsel * 65536 + 32768);
        const float of = -zz * sc;
        uint4 v;
        v = dqw(g2d.x, sc, of);
        *(uint4*)(&dB[br * 64 + (((bc0 + 0) ^ r7) << 3)]) = v;
        v = dqw(g2d.y, sc, of);
        *(uint4*)(&dB[br * 64 + (((bc0 + 1) ^ r7) << 3)]) = v;
        v = dqw(g2d.z, sc, of);
        *(uint4*)(&dB[br * 64 + (((bc0 + 2) ^ r7) << 3)]) = v;
        v = dqw(g2d.w, sc, of);
        *(uint4*)(&dB[br * 64 + (((bc0 + 3) ^ r7) << 3)]) = v;
    };

    const int NK = INTR / 64;   // 224

    if constexpr (MODE == 0) {
        STAGE_A(0, 0);
        STAGE_B(0, 0);
    } else {
        LOADB(0);
        STAGE_A(0, 0);
        DEQWB(0);
    }
    __syncthreads();

    for (int ks = 0; ks < NK; ++ks) {
        const int nxt = ks + 1 < NK ? ks + 1 : NK - 1;
        const int cur = ks & 1;

        if constexpr (MODE == 0) {
            STAGE_A(nxt, cur ^ 1);
            STAGE_B(nxt, cur ^ 1);
        } else {
            LOADB(nxt);
            STAGE_A(nxt, cur ^ 1);
        }

        const u16* bA = (const u16*)(smem + cur * 65536);
        const u16* bB = (const u16*)(smem + cur * 65536 + 32768);

#pragma unroll
        for (int kk = 0; kk < 2; ++kk) {
            short8 af[8], bf[4];
#pragma unroll
            for (int m = 0; m < 8; ++m) {
                int row = wr * 128 + m * 16 + fr;
                af[m] = *(const short8*)(&bA[row * 64 + ((((kk << 2) | fq) ^ (row & 7)) << 3)]);
            }
#pragma unroll
            for (int n = 0; n < 4; ++n) {
                int row = wc * 64 + n * 16 + fr;
                bf[n] = *(const short8*)(&bB[row * 64 + ((((kk << 2) | fq) ^ (row & 7)) << 3)]);
            }
#pragma unroll
            for (int m = 0; m < 8; ++m)
#pragma unroll
                for (int n = 0; n < 4; ++n)
                    acc[m][n] = __builtin_amdgcn_mfma_f32_16x16x32_bf16(af[m], bf[n], acc[m][n], 0, 0, 0);
        }

        if constexpr (MODE == 1) DEQWB(cur ^ 1);
        __syncthreads();
    }

    // -- epilogue: swizzled fp32 LDS stage, two 128-row passes --
    float* sO = (float*)smem;   // [128][256] f32 = 128 KB
#pragma unroll
    for (int half = 0; half < 2; ++half) {
        if (half) __syncthreads();
        if (wr == half) {
#pragma unroll
            for (int m = 0; m < 8; ++m)
#pragma unroll
                for (int n = 0; n < 4; ++n)
#pragma unroll
                    for (int r = 0; r < 4; ++r) {
                        int lr = m * 16 + fq * 4 + r;
                        int lc = wc * 64 + n * 16 + fr;
                        int cs = ((((lc >> 2) ^ (lr & 7)) << 2) | (lc & 3));
                        sO[lr * 256 + cs] = acc[m][n][r];
                    }
        }
        __syncthreads();
#pragma unroll
        for (int it = 0; it < 16; ++it) {
            int idx = it * 512 + tid;
            int row = idx >> 6;
            int ch  = idx & 63;
            float4 v = ((const float4*)sO)[row * 64 + (ch ^ (row & 7))];
            *(float4*)(&out[(size_t)(row0 + half * 128 + row) * HID + col0 + (ch << 2)]) = v;
        }
    }
}

// ---- launcher --------------------------------------------------------------

extern "C" void kernel_launch(void* const* d_in, const int* in_sizes, int n_in,
                              void* d_out, int out_size, void* d_ws, size_t ws_size,
                              hipStream_t stream) {
    (void)in_sizes; (void)n_in; (void)out_size;

    const float* hs  = (const float*)d_in[0];
    const int*   w1q = (const int*)  d_in[1];
    const float* w1s = (const float*)d_in[2];
    const float* w1z = (const float*)d_in[3];
    const int*   w3q = (const int*)  d_in[4];
    const float* w3s = (const float*)d_in[5];
    const float* w3z = (const float*)d_in[6];
    const int*   w2q = (const int*)  d_in[7];
    const float* w2s = (const float*)d_in[8];
    const float* w2z = (const float*)d_in[9];
    float* out = (float*)d_out;

    const size_t NWRD  = (size_t)INTR * HID / 8;
    const size_t SZ_HSB  = (size_t)TOK * HID;
    const size_t SZ_HMID = (size_t)TOK * INTR;
    const size_t SZ_WB   = (size_t)INTR * HID;

    u16* hsb  = (u16*)d_ws;                        // 4-chunk pre-swizzled bf16
    u16* hmid = hsb + SZ_HSB;                      // 8-chunk pre-swizzled bf16
    u16* wb1  = hmid + SZ_HMID;                    // w1 bf16 4-chunk (later w2 8-chunk)
    u16* wb3  = wb1 + SZ_WB;                       // w3 bf16 4-chunk
    u32* w1p  = (u32*)wb1;
    u32* w3p  = w1p + NWRD;
    u32* w2p  = w3p + NWRD;

    const size_t needF = (SZ_HSB + SZ_HMID + 2 * SZ_WB) * 2;
    const size_t needP = (SZ_HSB + SZ_HMID) * 2 + 3 * NWRD * 4;

    cvt_hs_kernel<<<(TOK * HID / 8) / 256, 256, 0, stream>>>(hs, hsb);

    dim3 g2(TOK / 256, INTR / 128);
    dim3 g3(TOK / 256, HID / 256);

    if (ws_size >= needF) {
        dqw_kernel<1><<<dim3(HID / 8 / 256, INTR), 256, 0, stream>>>(w1q, w1s, w1z, wb1, HID);
        dqw_kernel<1><<<dim3(HID / 8 / 256, INTR), 256, 0, stream>>>(w3q, w3s, w3z, wb3, HID);
        gateup_kernel<0><<<g2, 512, 0, stream>>>(hsb, wb1, wb3, nullptr, nullptr,
                                                 nullptr, nullptr, nullptr, nullptr, hmid);
        dqw_kernel<0><<<dim3(INTR / 8 / 256, HID), 256, 0, stream>>>(w2q, w2s, w2z, wb1, INTR);
        down_kernel<0><<<g3, 512, 0, stream>>>(hmid, wb1, nullptr, nullptr, nullptr, out);
    } else if (ws_size >= needP) {
        const int pgrid = (int)(NWRD / 256);
        pack_kernel<<<pgrid, 256, 0, stream>>>(w1q, w1p);
        pack_kernel<<<pgrid, 256, 0, stream>>>(w3q, w3p);
        pack_kernel<<<pgrid, 256, 0, stream>>>(w2q, w2p);
        gateup_kernel<1><<<g2, 512, 0, stream>>>(hsb, nullptr, nullptr, w1p, w3p,
                                                 w1s, w1z, w3s, w3z, hmid);
        down_kernel<1><<<g3, 512, 0, stream>>>(hmid, nullptr, w2p, w2s, w2z, out);
    }
}

// Round 15
// 1339.623 us; speedup vs baseline: 1.2389x; 1.0329x over previous
//
#include <hip/hip_runtime.h>
#include <hip/hip_bf16.h>
#include <stdint.h>

#define HID  4096
#define INTR 14336
#define GS   64
#define TOK  4096
#define GRP1 (HID / GS)
#define GRP2 (INTR / GS)

#define BK 64

typedef __attribute__((ext_vector_type(8))) short short8;  // 8 bf16
typedef __attribute__((ext_vector_type(4))) float f32x4;   // 16x16 MFMA acc
typedef unsigned short u16;
typedef unsigned int   u32;

// ---- helpers -------------------------------------------------------------

__device__ __forceinline__ u16 f2b(float x) {
    return __builtin_bit_cast(u16, __float2bfloat16(x));
}
__device__ __forceinline__ u32 pk2(float a, float b) {
    return (u32)f2b(a) | ((u32)f2b(b) << 16);
}
__device__ __forceinline__ u32 dq2(int ca, int cb, float s, float off) {
    return pk2(fmaf((float)ca, s, off), fmaf((float)cb, s, off));
}
__device__ __forceinline__ uint4 dqw(u32 w, float s, float off) {
    uint4 v;
    v.x = dq2((int)( w        & 15), (int)((w >>  4) & 15), s, off);
    v.y = dq2((int)((w >>  8) & 15), (int)((w >> 12) & 15), s, off);
    v.z = dq2((int)((w >> 16) & 15), (int)((w >> 20) & 15), s, off);
    v.w = dq2((int)((w >> 24) & 15), (int)( w >> 28       ), s, off);
    return v;
}
__device__ __forceinline__ void gload16(const void* g, void* l) {
    __builtin_amdgcn_global_load_lds(
        (const __attribute__((address_space(1))) void*)g,
        (__attribute__((address_space(3))) void*)l, 16, 0, 0);
}

// ---- weight dequant: int32 codes -> bf16, 8-chunk PRE-SWIZZLE -------------
// position = (c & ~7) | ((c&7) ^ (r&7))  — matches the GEMM's LDS read XOR.
// Dual variant: blockIdx.z selects (q0,o0) vs (q1,o1), halving launches.

__global__ void dqw2x_kernel(const int* __restrict__ q0, const float* __restrict__ s0,
                             const float* __restrict__ z0, u16* __restrict__ o0,
                             const int* __restrict__ q1, const float* __restrict__ s1,
                             const float* __restrict__ z1, u16* __restrict__ o1,
                             int cols) {
    const int*   q = blockIdx.z ? q1 : q0;
    const float* s = blockIdx.z ? s1 : s0;
    const float* z = blockIdx.z ? z1 : z0;
    u16*         o = blockIdx.z ? o1 : o0;
    int c = blockIdx.x * blockDim.x + threadIdx.x;   // 8-elem chunk in row
    int r = blockIdx.y;
    int grp = cols >> 6;
    const int* src = q + (size_t)r * cols + ((size_t)c << 3);
    int4 a = *(const int4*)src;
    int4 b = *(const int4*)(src + 4);
    float sc = s[(size_t)r * grp + (c >> 3)];
    float zz = z[(size_t)r * grp + (c >> 3)];
    float of = -zz * sc;
    uint4 v;
    v.x = dq2(a.x, a.y, sc, of);
    v.y = dq2(a.z, a.w, sc, of);
    v.z = dq2(b.x, b.y, sc, of);
    v.w = dq2(b.z, b.w, sc, of);
    int cs = (c & ~7) | ((c & 7) ^ (r & 7));
    *(uint4*)(o + (size_t)r * cols + ((size_t)cs << 3)) = v;
}

// ---- repack (fallback): int32 -> 8x 4-bit nibbles per u32 -----------------

__global__ void pack_kernel(const int* __restrict__ q, u32* __restrict__ p) {
    int i = blockIdx.x * blockDim.x + threadIdx.x;
    const int4* s = (const int4*)q + (size_t)i * 2;
    int4 a = s[0], b = s[1];
    u32 w = (u32)(a.x & 15)        | ((u32)(a.y & 15) << 4)
          | ((u32)(a.z & 15) << 8) | ((u32)(a.w & 15) << 12)
          | ((u32)(b.x & 15) << 16)| ((u32)(b.y & 15) << 20)
          | ((u32)(b.z & 15) << 24)| ((u32)(b.w & 15) << 28);
    p[i] = w;
}

// ---- hs fp32 -> bf16, 8-chunk PRE-SWIZZLE ---------------------------------

__global__ void cvt_hs_kernel(const float* __restrict__ x, u16* __restrict__ y) {
    int i = blockIdx.x * blockDim.x + threadIdx.x;   // one 8-elem chunk
    int t = i >> 9;            // HID/8 = 512 chunks per row
    int c = i & 511;
    const float4* xp = (const float4*)x + (size_t)i * 2;
    float4 a = xp[0], b = xp[1];
    uint4 o;
    o.x = pk2(a.x, a.y); o.y = pk2(a.z, a.w);
    o.z = pk2(b.x, b.y); o.w = pk2(b.z, b.w);
    int cs = (c & ~7) | ((c & 7) ^ (t & 7));
    ((uint4*)y)[(size_t)t * 512 + cs] = o;
}

// ---- kernel 2: fused gate+up dual GEMM + SiLU*mul (r12/r6 configuration) --
// BM=256 BN=128 BK=64, 8 waves (4Mx2N), wave tile 64x64, 16x16x32 MFMA.
// MODE 0: A and B staged via global_load_lds from pre-swizzled bf16;
//         double-buffered LDS, ONE barrier per K-step, no setprio.
// MODE 1: B dequanted from packed nibbles (fallback).

template<int MODE>
__global__ __launch_bounds__(512) void gateup_kernel(
    const u16* __restrict__ hsb,
    const u16* __restrict__ w1b, const u16* __restrict__ w3b,
    const u32* __restrict__ w1p, const u32* __restrict__ w3p,
    const float* __restrict__ s1, const float* __restrict__ z1,
    const float* __restrict__ s3, const float* __restrict__ z3,
    u16* __restrict__ hout)
{
    __shared__ __align__(16) char smem[131072];   // 2 x (A 32K | B1 16K | B3 16K)

    const int tid  = threadIdx.x;
    const int row0 = blockIdx.x * 256;
    const int col0 = blockIdx.y * 128;

    const int l   = tid & 63;
    const int wid = tid >> 6;
    const int wr  = wid >> 1;
    const int wc  = wid & 1;
    const int fq  = l >> 4;
    const int fr  = l & 15;

    f32x4 accg[4][4];
    f32x4 accu[4][4];
#pragma unroll
    for (int m = 0; m < 4; ++m)
#pragma unroll
        for (int n = 0; n < 4; ++n) {
            accg[m][n] = (f32x4){0.f, 0.f, 0.f, 0.f};
            accu[m][n] = (f32x4){0.f, 0.f, 0.f, 0.f};
        }

    // A staging source: lane covers row (blk*8 + l>>3), chunk (l&7)
    const u16* aSrc  = hsb + (size_t)(row0 + (l >> 3)) * HID + ((l & 7) << 3);
    const u16* b1Src = w1b + (size_t)(col0 + (l >> 3)) * HID + ((l & 7) << 3);
    const u16* b3Src = w3b + (size_t)(col0 + (l >> 3)) * HID + ((l & 7) << 3);

    // MODE 1 state
    const int br  = tid >> 2;
    const int bc0 = (tid & 3) << 1;
    const int r7  = br & 7;
    const u32* pp1 = w1p + (size_t)(col0 + br) * (HID / 8) + ((tid & 3) << 1);
    const u32* pp3 = w3p + (size_t)(col0 + br) * (HID / 8) + ((tid & 3) << 1);
    const size_t sBase = (size_t)(col0 + br) * GRP1;
    uint2 g1, g3;
    float sc1, zz1, sc3, zz3;

    auto LOADB = [&](int KS) {
        g1 = *(const uint2*)(pp1 + KS * 8);
        g3 = *(const uint2*)(pp3 + KS * 8);
        sc1 = s1[sBase + KS]; zz1 = z1[sBase + KS];
        sc3 = s3[sBase + KS]; zz3 = z3[sBase + KS];
    };

    auto STAGE_A = [&](int KS, int bsel) {
        const int k0 = KS * BK;
        char* base = smem + bsel * 65536;
#pragma unroll
        for (int i = 0; i < 4; ++i) {
            int blk = wid * 4 + i;                       // 8-row block 0..31
            gload16(aSrc + (size_t)(blk * 8) * HID + k0, base + (blk << 10));
        }
    };

    auto STAGE_B = [&](int KS, int bsel) {
        const int k0 = KS * BK;
        char* base = smem + bsel * 65536;
#pragma unroll
        for (int i = 0; i < 2; ++i) {
            int blk = wid * 2 + i;                       // 8-row block 0..15
            gload16(b1Src + (size_t)(blk * 8) * HID + k0, base + 32768 + (blk << 10));
            gload16(b3Src + (size_t)(blk * 8) * HID + k0, base + 49152 + (blk << 10));
        }
    };

    auto DEQWB = [&](int bsel) {
        u16* dB1 = (u16*)(smem + bsel * 65536 + 32768);
        u16* dB3 = (u16*)(smem + bsel * 65536 + 49152);
        const float of1 = -zz1 * sc1;
        const float of3 = -zz3 * sc3;
        uint4 lo, hi;
        lo = dqw(g1.x, sc1, of1);
        hi = dqw(g1.y, sc1, of1);
        *(uint4*)(&dB1[br * BK + (( bc0      ^ r7) << 3)]) = lo;
        *(uint4*)(&dB1[br * BK + (((bc0 + 1) ^ r7) << 3)]) = hi;
        lo = dqw(g3.x, sc3, of3);
        hi = dqw(g3.y, sc3, of3);
        *(uint4*)(&dB3[br * BK + (( bc0      ^ r7) << 3)]) = lo;
        *(uint4*)(&dB3[br * BK + (((bc0 + 1) ^ r7) << 3)]) = hi;
    };

    const int NK = HID / BK;   // 64

    if constexpr (MODE == 0) {
        STAGE_A(0, 0);
        STAGE_B(0, 0);
    } else {
        LOADB(0);
        STAGE_A(0, 0);
        DEQWB(0);
    }
    __syncthreads();

    for (int ks = 0; ks < NK; ++ks) {
        const int nxt = ks + 1 < NK ? ks + 1 : NK - 1;
        const int cur = ks & 1;

        if constexpr (MODE == 0) {
            STAGE_A(nxt, cur ^ 1);
            STAGE_B(nxt, cur ^ 1);
        } else {
            LOADB(nxt);
            STAGE_A(nxt, cur ^ 1);
        }

        const u16* bA  = (const u16*)(smem + cur * 65536);
        const u16* bB1 = (const u16*)(smem + cur * 65536 + 32768);
        const u16* bB3 = (const u16*)(smem + cur * 65536 + 49152);

#pragma unroll
        for (int kk = 0; kk < 2; ++kk) {
            short8 af[4], b1f[4], b3f[4];
#pragma unroll
            for (int m = 0; m < 4; ++m) {
                int row = wr * 64 + m * 16 + fr;
                af[m] = *(const short8*)(&bA[row * BK + ((((kk << 2) | fq) ^ (row & 7)) << 3)]);
            }
#pragma unroll
            for (int n = 0; n < 4; ++n) {
                int row = wc * 64 + n * 16 + fr;
                int ch  = (((kk << 2) | fq) ^ (row & 7)) << 3;
                b1f[n] = *(const short8*)(&bB1[row * BK + ch]);
                b3f[n] = *(const short8*)(&bB3[row * BK + ch]);
            }
#pragma unroll
            for (int m = 0; m < 4; ++m)
#pragma unroll
                for (int n = 0; n < 4; ++n) {
                    accg[m][n] = __builtin_amdgcn_mfma_f32_16x16x32_bf16(af[m], b1f[n], accg[m][n], 0, 0, 0);
                    accu[m][n] = __builtin_amdgcn_mfma_f32_16x16x32_bf16(af[m], b3f[n], accu[m][n], 0, 0, 0);
                }
        }

        if constexpr (MODE == 1) DEQWB(cur ^ 1);
        __syncthreads();
    }

    // -- epilogue: silu(g)*u -> swizzled LDS stage -> coalesced stores.
    //    (hmid stays 8-chunk pre-swizzled for the down kernel's DMA staging)
    u16* sO = (u16*)smem;    // [256][128] bf16 = 64 KB
#pragma unroll
    for (int m = 0; m < 4; ++m)
#pragma unroll
        for (int n = 0; n < 4; ++n)
#pragma unroll
            for (int r = 0; r < 4; ++r) {
                int lr = wr * 64 + m * 16 + fq * 4 + r;
                int lc = wc * 64 + n * 16 + fr;
                float g = accg[m][n][r];
                float u = accu[m][n][r];
                float hv = (g / (1.0f + __expf(-g))) * u;
                int cs = ((((lc >> 3) ^ (lr & 7)) << 3) | (lc & 7));
                sO[lr * 128 + cs] = f2b(hv);
            }
    __syncthreads();
#pragma unroll
    for (int it = 0; it < 8; ++it) {
        int idx = it * 512 + tid;          // 16B units
        int row = idx >> 4;
        int cu  = idx & 15;
        uint4 v = ((const uint4*)sO)[row * 16 + cu];
        *(uint4*)(&hout[(size_t)(row0 + row) * INTR + col0 + (cu << 3)]) = v;
    }
}

// ---- kernel 3: down proj (r12 verbatim — measured best) --------------------
// BM=256 BN=256 BK=64, 8 waves (2Mx4N), wave tile 128x64, 16x16x32 MFMA.

template<int MODE>
__global__ __launch_bounds__(512) void down_kernel(
    const u16* __restrict__ hb,
    const u16* __restrict__ w2b, const u32* __restrict__ w2p,
    const float* __restrict__ s2, const float* __restrict__ z2,
    float* __restrict__ out)
{
    __shared__ __align__(16) char smem[131072];   // 2 x (A 32K | B 32K)

    const int tid  = threadIdx.x;
    const int row0 = blockIdx.x * 256;
    const int col0 = blockIdx.y * 256;

    const int l   = tid & 63;
    const int wid = tid >> 6;
    const int wr  = wid >> 2;      // 0..1 (M, 128 rows each)
    const int wc  = wid & 3;       // 0..3 (N, 64 cols each)
    const int fq  = l >> 4;
    const int fr  = l & 15;

    f32x4 acc[8][4];
#pragma unroll
    for (int m = 0; m < 8; ++m)
#pragma unroll
        for (int n = 0; n < 4; ++n)
            acc[m][n] = (f32x4){0.f, 0.f, 0.f, 0.f};

    const u16* aSrc = hb  + (size_t)(row0 + (l >> 3)) * INTR + ((l & 7) << 3);
    const u16* bSrc = w2b + (size_t)(col0 + (l >> 3)) * INTR + ((l & 7) << 3);

    const int br  = tid >> 1;
    const int bc0 = (tid & 1) << 2;
    const int r7  = br & 7;
    const u32* pp2 = w2p + (size_t)(col0 + br) * (INTR / 8) + bc0;
    const size_t sBase = (size_t)(col0 + br) * GRP2;
    uint4 g2d;
    float sc, zz;

    auto LOADB = [&](int KS) {
        g2d = *(const uint4*)(pp2 + KS * 8);
        sc = s2[sBase + KS]; zz = z2[sBase + KS];
    };

    auto STAGE_A = [&](int KS, int bsel) {
        const int k0 = KS * BK;
        char* base = smem + bsel * 65536;
#pragma unroll
        for (int i = 0; i < 4; ++i) {
            int blk = wid * 4 + i;
            gload16(aSrc + (size_t)(blk * 8) * INTR + k0, base + (blk << 10));
        }
    };

    auto STAGE_B = [&](int KS, int bsel) {
        const int k0 = KS * BK;
        char* base = smem + bsel * 65536;
#pragma unroll
        for (int i = 0; i < 4; ++i) {
            int blk = wid * 4 + i;
            gload16(bSrc + (size_t)(blk * 8) * INTR + k0, base + 32768 + (blk << 10));
        }
    };

    auto DEQWB = [&](int bsel) {
        u16* dB = (u16*)(smem + bsel * 65536 + 32768);
        const float of = -zz * sc;
        uint4 v;
        v = dqw(g2d.x, sc, of);
        *(uint4*)(&dB[br * BK + (((bc0 + 0) ^ r7) << 3)]) = v;
        v = dqw(g2d.y, sc, of);
        *(uint4*)(&dB[br * BK + (((bc0 + 1) ^ r7) << 3)]) = v;
        v = dqw(g2d.z, sc, of);
        *(uint4*)(&dB[br * BK + (((bc0 + 2) ^ r7) << 3)]) = v;
        v = dqw(g2d.w, sc, of);
        *(uint4*)(&dB[br * BK + (((bc0 + 3) ^ r7) << 3)]) = v;
    };

    const int NK = INTR / BK;   // 224

    if constexpr (MODE == 0) {
        STAGE_A(0, 0);
        STAGE_B(0, 0);
    } else {
        LOADB(0);
        STAGE_A(0, 0);
        DEQWB(0);
    }
    __syncthreads();

    for (int ks = 0; ks < NK; ++ks) {
        const int nxt = ks + 1 < NK ? ks + 1 : NK - 1;
        const int cur = ks & 1;

        if constexpr (MODE == 0) {
            STAGE_A(nxt, cur ^ 1);
            STAGE_B(nxt, cur ^ 1);
        } else {
            LOADB(nxt);
            STAGE_A(nxt, cur ^ 1);
        }

        const u16* bA = (const u16*)(smem + cur * 65536);
        const u16* bB = (const u16*)(smem + cur * 65536 + 32768);

#pragma unroll
        for (int kk = 0; kk < 2; ++kk) {
            short8 af[8], bf[4];
#pragma unroll
            for (int m = 0; m < 8; ++m) {
                int row = wr * 128 + m * 16 + fr;
                af[m] = *(const short8*)(&bA[row * BK + ((((kk << 2) | fq) ^ (row & 7)) << 3)]);
            }
#pragma unroll
            for (int n = 0; n < 4; ++n) {
                int row = wc * 64 + n * 16 + fr;
                bf[n] = *(const short8*)(&bB[row * BK + ((((kk << 2) | fq) ^ (row & 7)) << 3)]);
            }
#pragma unroll
            for (int m = 0; m < 8; ++m)
#pragma unroll
                for (int n = 0; n < 4; ++n)
                    acc[m][n] = __builtin_amdgcn_mfma_f32_16x16x32_bf16(af[m], bf[n], acc[m][n], 0, 0, 0);
        }

        if constexpr (MODE == 1) DEQWB(cur ^ 1);
        __syncthreads();
    }

    // -- epilogue: swizzled fp32 LDS stage, two 128-row passes --
    float* sO = (float*)smem;   // [128][256] f32 = 128 KB
#pragma unroll
    for (int half = 0; half < 2; ++half) {
        if (half) __syncthreads();
        if (wr == half) {
#pragma unroll
            for (int m = 0; m < 8; ++m)
#pragma unroll
                for (int n = 0; n < 4; ++n)
#pragma unroll
                    for (int r = 0; r < 4; ++r) {
                        int lr = m * 16 + fq * 4 + r;
                        int lc = wc * 64 + n * 16 + fr;
                        int cs = ((((lc >> 2) ^ (lr & 7)) << 2) | (lc & 3));
                        sO[lr * 256 + cs] = acc[m][n][r];
                    }
        }
        __syncthreads();
#pragma unroll
        for (int it = 0; it < 16; ++it) {
            int idx = it * 512 + tid;
            int row = idx >> 6;
            int ch  = idx & 63;
            float4 v = ((const float4*)sO)[row * 64 + (ch ^ (row & 7))];
            *(float4*)(&out[(size_t)(row0 + half * 128 + row) * HID + col0 + (ch << 2)]) = v;
        }
    }
}

// ---- launcher --------------------------------------------------------------

extern "C" void kernel_launch(void* const* d_in, const int* in_sizes, int n_in,
                              void* d_out, int out_size, void* d_ws, size_t ws_size,
                              hipStream_t stream) {
    (void)in_sizes; (void)n_in; (void)out_size;

    const float* hs  = (const float*)d_in[0];
    const int*   w1q = (const int*)  d_in[1];
    const float* w1s = (const float*)d_in[2];
    const float* w1z = (const float*)d_in[3];
    const int*   w3q = (const int*)  d_in[4];
    const float* w3s = (const float*)d_in[5];
    const float* w3z = (const float*)d_in[6];
    const int*   w2q = (const int*)  d_in[7];
    const float* w2s = (const float*)d_in[8];
    const float* w2z = (const float*)d_in[9];
    float* out = (float*)d_out;

    const size_t NWRD  = (size_t)INTR * HID / 8;
    const size_t SZ_HSB  = (size_t)TOK * HID;
    const size_t SZ_HMID = (size_t)TOK * INTR;
    const size_t SZ_WB   = (size_t)INTR * HID;

    u16* hsb  = (u16*)d_ws;                        // 8-chunk pre-swizzled bf16
    u16* hmid = hsb + SZ_HSB;                      // 8-chunk pre-swizzled bf16
    u16* wb1  = hmid + SZ_HMID;                    // w1 bf16 (later w2 bf16)
    u16* wb3  = wb1 + SZ_WB;                       // w3 bf16
    u32* w1p  = (u32*)wb1;
    u32* w3p  = w1p + NWRD;
    u32* w2p  = w3p + NWRD;

    const size_t needF = (SZ_HSB + SZ_HMID + 2 * SZ_WB) * 2;
    const size_t needP = (SZ_HSB + SZ_HMID) * 2 + 3 * NWRD * 4;

    cvt_hs_kernel<<<(TOK * HID / 8) / 256, 256, 0, stream>>>(hs, hsb);

    dim3 g2(TOK / 256, INTR / 128);
    dim3 g3(TOK / 256, HID / 256);

    if (ws_size >= needF) {
        // w1 and w3 dequant in a single launch (blockIdx.z selects tensor)
        dqw2x_kernel<<<dim3(HID / 8 / 256, INTR, 2), 256, 0, stream>>>(
            w1q, w1s, w1z, wb1, w3q, w3s, w3z, wb3, HID);
        gateup_kernel<0><<<g2, 512, 0, stream>>>(hsb, wb1, wb3, nullptr, nullptr,
                                                 nullptr, nullptr, nullptr, nullptr, hmid);
        // w2 dequant AFTER gateup: aliases wb1's region (stream-ordered)
        dqw2x_kernel<<<dim3(INTR / 8 / 256, HID, 1), 256, 0, stream>>>(
            w2q, w2s, w2z, wb1, nullptr, nullptr, nullptr, nullptr, INTR);
        down_kernel<0><<<g3, 512, 0, stream>>>(hmid, wb1, nullptr, nullptr, nullptr, out);
    } else if (ws_size >= needP) {
        const int pgrid = (int)(NWRD / 256);
        pack_kernel<<<pgrid, 256, 0, stream>>>(w1q, w1p);
        pack_kernel<<<pgrid, 256, 0, stream>>>(w3q, w3p);
        pack_kernel<<<pgrid, 256, 0, stream>>>(w2q, w2p);
        gateup_kernel<1><<<g2, 512, 0, stream>>>(hsb, nullptr, nullptr, w1p, w3p,
                                                 w1s, w1z, w3s, w3z, hmid);
        down_kernel<1><<<g3, 512, 0, stream>>>(hmid, nullptr, w2p, w2s, w2z, out);
    }
}